// Round 13
// baseline (499.267 us; speedup 1.0000x reference)
//
#include <hip/hip_runtime.h>

#define HSZ  32
#define TLEN 1024
#define PS   40   // f16 stride per col in a plane (80 B: 16B-aligned b128 reads)

typedef _Float16 half8 __attribute__((ext_vector_type(8)));
typedef float    f32x4 __attribute__((ext_vector_type(4)));

__device__ __forceinline__ float rcp_f(float x){ return __builtin_amdgcn_rcpf(x); }
__device__ __forceinline__ float exp2_f(float x){ return __builtin_amdgcn_exp2f(x); }
#define SCL_S (-1.442695040888963f)   // sigmoid arg prescale: -log2(e)
#define SCL_T ( 2.885390081777927f)   // tanh arg prescale: +2*log2(e)

__device__ __forceinline__ f32x4 mfma16(half8 a, half8 b, f32x4 c){
  return __builtin_amdgcn_mfma_f32_16x16x32_f16(a, b, c, 0, 0, 0);
}
// LDS-only barrier: drain lgkmcnt (ds reads AND writes) without draining vmcnt,
// so the x global prefetch stays in flight across step barriers.
__device__ __forceinline__ void lds_barrier(){
  asm volatile("s_waitcnt lgkmcnt(0)\n\ts_barrier" ::: "memory");
}

// gate quad from prescaled args; paired rcps; updates CV in place.
#define ACT4(A0,A1,A2,A3, CV, OV)                              \
  float OV;                                                    \
  { float Zi_ = exp2_f(A0), Zf_ = exp2_f(A1);                  \
    float Zg_ = exp2_f(A2), Zo_ = exp2_f(A3);                  \
    float di_ = 1.f+Zi_, df_ = 1.f+Zf_;                        \
    float dg_ = 1.f+Zg_, dq_ = 1.f+Zo_;                        \
    float r1_ = rcp_f(di_*df_);                                \
    float IV_ = r1_*df_, FV_ = r1_*di_;                        \
    float r2_ = rcp_f(dg_*dq_);                                \
    float GV_ = fmaf(-2.f, r2_*dq_, 1.f); OV = r2_*dg_;        \
    CV = fmaf(FV_, CV, IV_*GV_); }

// h = o * tanh(c), prescaled: tanh = 1 - 2*rcp(1+exp2(SCL_T*c))
#define HOUT(CV, OV, HV)                                       \
  { float Zc_ = exp2_f(SCL_T*(CV));                            \
    float rc_ = rcp_f(1.f + Zc_);                              \
    HV = fmaf(-2.f, rc_*(OV), OV); }

// SPLIT-PHASE SCHEDULE, 8 combined waves / 16-batch tile (2 waves/SIMD):
// iteration t:
//   Q: L1(t)   -- u=WHh,WHl x Bh1(t-1) [regs]; v=WIh,WIl x Bh0(t) [regs];
//                 acts -> h1(t); ds_write H1.            BAR-A (lgkm drain)
//   P: L0(t+1) -- e=W0h,W0l x Bh0(t) [same regs]; ISSUE ds_read Bh1 <- H1
//                 (lands during acts); acts -> h0(t+1); ds_write H0.
//                                                        BAR-B (lgkm drain)
//   ISSUE ds_read Bh0 <- H0 (lands during next Q's u-chain).
// Every ds_read issues >=1 region before first use -> LDS latency off the
// critical chain. SINGLE-buffered planes are race-free because each barrier's
// lgkmcnt(0) drains outstanding reads before the next write to that plane:
//   W1 -> BAR-A -> R1 (issue); R1 drained at BAR-B; next W1 after BAR-B.  OK
//   W0 -> BAR-B -> R0 (issue); R0 drained at BAR-A; next W0 after BAR-A.  OK
// Permuted A-rows (32*(r&3)+4w+(r>>2)): lane (g,c) D-regs j=0..3 = gates
// (i,f,g,o) of state s=4w+g -- quad in-lane. h f16-hi only; weights hi+lo.
__global__ __launch_bounds__(512, 2) void lstm2_sp(
    const float* __restrict__ x,
    const float* __restrict__ Wih0, const float* __restrict__ Whh0,
    const float* __restrict__ bih0, const float* __restrict__ bhh0,
    const float* __restrict__ Wih1, const float* __restrict__ Whh1,
    const float* __restrict__ bih1, const float* __restrict__ bhh1,
    const float* __restrict__ Wfc,  const float* __restrict__ bfc,
    float* __restrict__ out, int Tn)
{
  __shared__ __align__(16) _Float16 H0[16*PS];   // h0 plane [col*PS + k]
  __shared__ __align__(16) _Float16 H1[16*PS];   // h1 plane
  __shared__ float sc[32*17];                    // FC scratch (separate, small)

  const int tid = threadIdx.x;
  const int w   = tid >> 6;
  const int l   = tid & 63;
  const int c   = l & 15;        // batch col == A tile-row index
  const int g   = l >> 4;        // k-group == D row-group
  const int s   = 4*w + g;       // state this lane owns
  const int b0  = blockIdx.x * 16;

  // ---- A fragments: hi+lo split, prescaled, permuted rows, k = 8g+j ----
  const int prow = 32*(c & 3) + 4*w + (c >> 2);
  const float sA = ((c & 3) == 2) ? SCL_T : SCL_S;
  half8 W0h, W0l, WIh, WIl, WHh, WHl;
  {
    const float* p0 = Whh0 + prow*HSZ + 8*g;
    const float* p1 = Wih1 + prow*HSZ + 8*g;
    const float* p2 = Whh1 + prow*HSZ + 8*g;
    #pragma unroll
    for (int j = 0; j < 8; ++j){
      float v0 = p0[j]*sA, v1 = p1[j]*sA, v2 = p2[j]*sA;
      _Float16 a = (_Float16)v0; W0h[j] = a; W0l[j] = (_Float16)(v0 - (float)a);
      _Float16 b = (_Float16)v1; WIh[j] = b; WIl[j] = (_Float16)(v1 - (float)b);
      _Float16 d = (_Float16)v2; WHh[j] = d; WHl[j] = (_Float16)(v2 - (float)d);
    }
  }
  // D reg j = physical gate row 32j + s; per-gate prescale (j=2 is tanh)
  const float scj[4] = {SCL_S, SCL_S, SCL_T, SCL_S};
  float wx[4], bs0[4];
  f32x4 bias1;
  #pragma unroll
  for (int j = 0; j < 4; ++j){
    int r    = 32*j + s;
    wx[j]    = Wih0[r] * scj[j];
    bs0[j]   = (bih0[r] + bhh0[r]) * scj[j];
    bias1[j] = (bih1[r] + bhh1[r]) * scj[j];
  }
  const f32x4 zero4 = {0.f, 0.f, 0.f, 0.f};

  const int wrI = c*PS + s;       // this lane's h write slot (f16 index)
  const int rdI = c*PS + 8*g;     // b128 read base (16B aligned)

  const float* xp = x + (size_t)(b0 + c) * Tn;
  float c0 = 0.f, c1 = 0.f;

  // ---- prologue: L0(0) (h0(-1)=0 -> no MFMA); write h0(0) ----
  {
    float x0 = xp[0];
    float a0 = fmaf(x0, wx[0], bs0[0]);
    float a1 = fmaf(x0, wx[1], bs0[1]);
    float a2 = fmaf(x0, wx[2], bs0[2]);
    float a3 = fmaf(x0, wx[3], bs0[3]);
    ACT4(a0, a1, a2, a3, c0, o0_);
    float h0;
    HOUT(c0, o0_, h0);
    H0[wrI] = (_Float16)h0;
  }
  __syncthreads();
  half8 Bh0 = *(const half8*)&H0[rdI];   // h0(0) frags
  half8 Bh1 = {};                         // h1(-1) = 0 (no LDS init needed)
  float xv = xp[1];                       // x(1), used in iteration 0's P

  float h1v = 0.f;
  const int Tm1 = Tn - 1;

  for (int t = 0; t < Tm1; ++t){
    // x prefetch for NEXT iteration's P (x(t+2)), clamped scalar offset
    int xi = t + 2; xi = (xi > Tm1) ? Tm1 : xi;
    float xn = xp[xi];                    // vmem, stays in flight across bars

    // ================= Q: L1(t) =================
    f32x4 u, vv;
    u  = mfma16(WHh, Bh1, bias1);
    u  = mfma16(WHl, Bh1, u);
    vv = mfma16(WIh, Bh0, zero4);
    vv = mfma16(WIl, Bh0, vv);
    f32x4 a = u + vv;
    ACT4(a[0], a[1], a[2], a[3], c1, o1_);
    HOUT(c1, o1_, h1v);
    H1[wrI] = (_Float16)h1v;

    lds_barrier();                        // BAR-A

    // ================= P: L0(t+1) =================
    f32x4 e;
    e[0] = fmaf(xv, wx[0], bs0[0]);
    e[1] = fmaf(xv, wx[1], bs0[1]);
    e[2] = fmaf(xv, wx[2], bs0[2]);
    e[3] = fmaf(xv, wx[3], bs0[3]);
    e = mfma16(W0h, Bh0, e);
    e = mfma16(W0l, Bh0, e);
    Bh1 = *(const half8*)&H1[rdI];        // issue read h1(t); lands during acts
    ACT4(e[0], e[1], e[2], e[3], c0, o0_);
    float h0;
    HOUT(c0, o0_, h0);
    H0[wrI] = (_Float16)h0;

    lds_barrier();                        // BAR-B

    Bh0 = *(const half8*)&H0[rdI];        // issue read h0(t+1); lands in next Q
    xv = xn;
  }

  // ---- final Q: L1(Tn-1) (no write needed) ----
  {
    f32x4 u, vv;
    u  = mfma16(WHh, Bh1, bias1);
    u  = mfma16(WHl, Bh1, u);
    vv = mfma16(WIh, Bh0, zero4);
    vv = mfma16(WIl, Bh0, vv);
    f32x4 a = u + vv;
    ACT4(a[0], a[1], a[2], a[3], c1, o1_);
    HOUT(c1, o1_, h1v);
  }

  // ---- FC head: out[b0+c] = dot(h1_final[:,c], Wfc) + bfc ----
  sc[s*17 + c] = h1v;
  __syncthreads();
  if (tid < 16){
    float acc = bfc[0];
    #pragma unroll 8
    for (int k = 0; k < HSZ; ++k) acc = fmaf(sc[k*17 + tid], Wfc[k], acc);
    out[b0 + tid] = acc;
  }
}

extern "C" void kernel_launch(void* const* d_in, const int* in_sizes, int n_in,
                              void* d_out, int out_size, void* d_ws, size_t ws_size,
                              hipStream_t stream) {
  const float* x    = (const float*)d_in[0];
  const float* Wih0 = (const float*)d_in[1];
  const float* Whh0 = (const float*)d_in[2];
  const float* bih0 = (const float*)d_in[3];
  const float* bhh0 = (const float*)d_in[4];
  const float* Wih1 = (const float*)d_in[5];
  const float* Whh1 = (const float*)d_in[6];
  const float* bih1 = (const float*)d_in[7];
  const float* bhh1 = (const float*)d_in[8];
  const float* Wfc  = (const float*)d_in[9];
  const float* bfc  = (const float*)d_in[10];
  float* out = (float*)d_out;

  const int Tn = TLEN;
  const int B  = in_sizes[0] / Tn;     // x is (B, T, 1)

  dim3 block(512);
  dim3 grid(B / 16);
  hipLaunchKernelGGL(lstm2_sp, grid, block, 0, stream,
                     x, Wih0, Whh0, bih0, bhh0, Wih1, Whh1, bih1, bhh1,
                     Wfc, bfc, out, Tn);
}

// Round 14
// 408.048 us; speedup vs baseline: 1.2235x; 1.2235x over previous
//
#include <hip/hip_runtime.h>

#define HSZ  32
#define TLEN 1024
#define PS   40   // f16 stride per col in a plane (80 B: 16B-aligned b128 reads)

typedef _Float16 half8 __attribute__((ext_vector_type(8)));
typedef float    f32x4 __attribute__((ext_vector_type(4)));

__device__ __forceinline__ float rcp_f(float x){ return __builtin_amdgcn_rcpf(x); }
__device__ __forceinline__ float exp2_f(float x){ return __builtin_amdgcn_exp2f(x); }
#define SCL_S (-1.442695040888963f)   // sigmoid arg prescale: -log2(e)
#define SCL_T ( 2.885390081777927f)   // tanh arg prescale: +2*log2(e)

__device__ __forceinline__ f32x4 mfma16(half8 a, half8 b, f32x4 c){
  return __builtin_amdgcn_mfma_f32_16x16x32_f16(a, b, c, 0, 0, 0);
}
// LDS-only barrier: drain lgkmcnt without draining vmcnt (x prefetch in flight).
__device__ __forceinline__ void lds_barrier(){
  asm volatile("s_waitcnt lgkmcnt(0)\n\ts_barrier" ::: "memory");
}

// gate quad from prescaled args; paired rcps; updates CV in place.
#define ACT4(A0,A1,A2,A3, CV, OV)                              \
  float OV;                                                    \
  { float Zi_ = exp2_f(A0), Zf_ = exp2_f(A1);                  \
    float Zg_ = exp2_f(A2), Zo_ = exp2_f(A3);                  \
    float di_ = 1.f+Zi_, df_ = 1.f+Zf_;                        \
    float dg_ = 1.f+Zg_, dq_ = 1.f+Zo_;                        \
    float r1_ = rcp_f(di_*df_);                                \
    float IV_ = r1_*df_, FV_ = r1_*di_;                        \
    float r2_ = rcp_f(dg_*dq_);                                \
    float GV_ = fmaf(-2.f, r2_*dq_, 1.f); OV = r2_*dg_;        \
    CV = fmaf(FV_, CV, IV_*GV_); }

// h = o * tanh(c), prescaled: tanh = 1 - 2*rcp(1+exp2(SCL_T*c))
#define HOUT(CV, OV, HV)                                       \
  { float Zc_ = exp2_f(SCL_T*(CV));                            \
    float rc_ = rcp_f(1.f + Zc_);                              \
    HV = fmaf(-2.f, rc_*(OV), OV); }

// 16 waves / 16-batch tile (4 waves/SIMD), R11 structure, polish pass:
//  - setprio REMOVED (m190: priority boosts hurt barrier-lockstep schedules)
//  - post-barrier ds_reads issued as the FIRST ops of each interval
//  waves 0-7  (L0): 1 permuted D-tile = 4 states, 2 MFMA/step.
//  waves 8-15 (L1): 1 D-tile = 4 states, 4 MFMA/step (Whh1*h1 + Wih1*h0).
// Permuted A-rows (32*(r&3)+4*tau+(r>>2)): lane (g,c) D-regs j=0..3 = gates
// (i,f,g,o) of state 4*tau+g -- quad in-lane, no gate LDS round-trip.
// h exchanged as f16-hi only; weights hi+lo split; one lgkm-only barrier/step;
// parity double-buffered planes.
__global__ __launch_bounds__(1024, 4) void lstm2_w16b(
    const float* __restrict__ x,
    const float* __restrict__ Wih0, const float* __restrict__ Whh0,
    const float* __restrict__ bih0, const float* __restrict__ bhh0,
    const float* __restrict__ Wih1, const float* __restrict__ Whh1,
    const float* __restrict__ bih1, const float* __restrict__ bhh1,
    const float* __restrict__ Wfc,  const float* __restrict__ bfc,
    float* __restrict__ out, int Tn)
{
  __shared__ __align__(16) _Float16 hpl[2][2][16*PS];  // [parity][layer][col*PS+k]

  const int tid = threadIdx.x;
  const int w   = tid >> 6;
  const int l   = tid & 63;
  const int col = l & 15;        // batch col == A tile-row index
  const int g   = l >> 4;        // k-group == D row-group
  const int b0  = blockIdx.x * 16;
  const bool isL0 = (w < 8);
  const int wl  = isL0 ? w : (w - 8);   // tile index 0..7
  const int st  = 4*wl + g;             // state this lane owns

  const int rdI = col*PS + 8*g;         // b128 read (16B-aligned)
  const int wrI = col*PS + st;          // this lane's h write
  const float sA = ((col & 3) == 2) ? SCL_T : SCL_S;
  const float scj[4] = {SCL_S, SCL_S, SCL_T, SCL_S};
  const f32x4 zero4 = {0.f, 0.f, 0.f, 0.f};
  const int prow = 32*(col & 3) + 4*wl + (col >> 2);

  for (int i = tid; i < 2*2*16*PS; i += 1024) (&hpl[0][0][0])[i] = (_Float16)0.0f;

  // ---- per-role weight/bias loads (divergent, no barrier inside) ----
  half8 WAh, WAl;                  // L0: Whh0 hi/lo | L1: Whh1 hi/lo
  half8 WIh, WIl;                  // L1 only: Wih1 hi/lo
  f32x4 bias1;                     // L1 only
  float wx[4], bs0[4];             // L0 only
  const float* xp = x + (size_t)(b0 + col) * Tn;

  if (isL0){
    const float* p0 = Whh0 + prow*HSZ + 8*g;
    #pragma unroll
    for (int j = 0; j < 8; ++j){
      float v0 = p0[j]*sA;
      _Float16 a = (_Float16)v0; WAh[j] = a; WAl[j] = (_Float16)(v0 - (float)a);
    }
    #pragma unroll
    for (int j = 0; j < 4; ++j){
      int r  = 32*j + st;
      wx[j]  = Wih0[r] * scj[j];
      bs0[j] = (bih0[r] + bhh0[r]) * scj[j];
    }
  } else {
    const float* pH = Whh1 + prow*HSZ + 8*g;
    const float* pI = Wih1 + prow*HSZ + 8*g;
    #pragma unroll
    for (int j = 0; j < 8; ++j){
      float v2 = pH[j]*sA, v1 = pI[j]*sA;
      _Float16 c = (_Float16)v2; WAh[j] = c; WAl[j] = (_Float16)(v2 - (float)c);
      _Float16 b = (_Float16)v1; WIh[j] = b; WIl[j] = (_Float16)(v1 - (float)b);
    }
    #pragma unroll
    for (int j = 0; j < 4; ++j){
      int r = 32*j + st;
      bias1[j] = (bih1[r] + bhh1[r]) * scj[j];
    }
  }

  float cSt = 0.f, hFin = 0.f;     // recurrent cell state / last h (per role)

  __syncthreads();   // [A] zero-init visible

  // ---- prologue: L0 computes h0(0) (no MFMA, h0(-1)=0); h1(-1)=0 already ----
  if (isL0){
    float x0 = xp[0];
    ACT4(fmaf(x0,wx[0],bs0[0]), fmaf(x0,wx[1],bs0[1]),
         fmaf(x0,wx[2],bs0[2]), fmaf(x0,wx[3],bs0[3]), cSt, ov0_);
    float h0;
    HOUT(cSt, ov0_, h0);
    hpl[0][0][wrI] = (_Float16)h0;
  }
  __syncthreads();   // [B] h0(0) visible

  if (isL0){
    // ================= LAYER-0 (1 tile, 2 MFMA/step) =================
    half8 Bh0 = *(const half8*)&hpl[0][0][rdI];   // h0(0)
    float xv = xp[1];

#define L0STEP(Q, XNI)                                                     \
    {                                                                      \
      float xn = xp[(XNI)];                                                \
      f32x4 e;                                                             \
      e[0]=fmaf(xv,wx[0],bs0[0]); e[1]=fmaf(xv,wx[1],bs0[1]);              \
      e[2]=fmaf(xv,wx[2],bs0[2]); e[3]=fmaf(xv,wx[3],bs0[3]);              \
      e = mfma16(WAh, Bh0, e);                                             \
      e = mfma16(WAl, Bh0, e);                                             \
      ACT4(e[0],e[1],e[2],e[3], cSt, ov_);                                 \
      float h0;                                                            \
      HOUT(cSt, ov_, h0);                                                  \
      hpl[(Q)][0][wrI] = (_Float16)h0;                                     \
      lds_barrier();                                                       \
      Bh0 = *(const half8*)&hpl[(Q)][0][rdI];                              \
      xv = xn;                                                             \
    }

    for (int T0 = 0; T0 < Tn; T0 += 2){
      L0STEP(1, (T0+2 < Tn) ? T0+2 : Tn-1);
      L0STEP(0, (T0+3 < Tn) ? T0+3 : Tn-1);
    }
#undef L0STEP
  } else {
    // ================= LAYER-1 (1 tile, 4 MFMA/step) =================
    half8 Bh0 = *(const half8*)&hpl[0][0][rdI];   // h0(0)
    half8 Bh1 = *(const half8*)&hpl[0][1][rdI];   // h1(-1) = 0

#define L1STEP(Q)                                                          \
    {                                                                      \
      f32x4 u, vv;                                                         \
      u  = mfma16(WAh, Bh1, bias1);                                        \
      vv = mfma16(WIh, Bh0, zero4);                                        \
      u  = mfma16(WAl, Bh1, u);                                            \
      vv = mfma16(WIl, Bh0, vv);                                           \
      f32x4 a = u + vv;                                                    \
      ACT4(a[0],a[1],a[2],a[3], cSt, ov_);                                 \
      HOUT(cSt, ov_, hFin);                                                \
      hpl[(Q)][1][wrI] = (_Float16)hFin;                                   \
      lds_barrier();                                                       \
      Bh0 = *(const half8*)&hpl[(Q)][0][rdI];                              \
      Bh1 = *(const half8*)&hpl[(Q)][1][rdI];                              \
    }

    for (int T0 = 0; T0 < Tn; T0 += 2){
      L1STEP(1);
      L1STEP(0);
    }
#undef L1STEP
  }

  // ---- FC head: out[b0+c] = dot(h1_final[:,c], Wfc) + bfc ----
  __syncthreads();   // [C] loops done everywhere
  float* sc = (float*)&hpl[0][0][0];
  if (!isL0){
    sc[st*17 + col] = hFin;
  }
  __syncthreads();   // [D]
  if (tid < 16){
    float acc = bfc[0];
    #pragma unroll 8
    for (int k = 0; k < HSZ; ++k) acc = fmaf(sc[k*17 + tid], Wfc[k], acc);
    out[b0 + tid] = acc;
  }
}

extern "C" void kernel_launch(void* const* d_in, const int* in_sizes, int n_in,
                              void* d_out, int out_size, void* d_ws, size_t ws_size,
                              hipStream_t stream) {
  const float* x    = (const float*)d_in[0];
  const float* Wih0 = (const float*)d_in[1];
  const float* Whh0 = (const float*)d_in[2];
  const float* bih0 = (const float*)d_in[3];
  const float* bhh0 = (const float*)d_in[4];
  const float* Wih1 = (const float*)d_in[5];
  const float* Whh1 = (const float*)d_in[6];
  const float* bih1 = (const float*)d_in[7];
  const float* bhh1 = (const float*)d_in[8];
  const float* Wfc  = (const float*)d_in[9];
  const float* bfc  = (const float*)d_in[10];
  float* out = (float*)d_out;

  const int Tn = TLEN;
  const int B  = in_sizes[0] / Tn;     // x is (B, T, 1)

  dim3 block(1024);
  dim3 grid(B / 16);
  hipLaunchKernelGGL(lstm2_w16b, grid, block, 0, stream,
                     x, Wih0, Whh0, bih0, bhh0, Wih1, Whh1, bih1, bhh1,
                     Wfc, bfc, out, Tn);
}